// Round 1
// baseline (178.792 us; speedup 1.0000x reference)
//
#include <hip/hip_runtime.h>
#include <hip/hip_bf16.h>

#define N 2048
#define FEAT 2048
#define K_NEG 10
#define M1 0.3f
#define M2 0.3f
#define CW 0.01f

typedef __attribute__((ext_vector_type(8))) __bf16 bf16x8;
typedef __attribute__((ext_vector_type(4))) float f32x4;

__device__ __forceinline__ unsigned short f32_to_bf16(float f) {
    unsigned int u = __float_as_uint(f);
    u += 0x7fffu + ((u >> 16) & 1u);   // round-to-nearest-even
    return (unsigned short)(u >> 16);
}

__device__ __forceinline__ unsigned int rotl32(unsigned int x, int d) {
    return (x << d) | (x >> (32 - d));
}

// Exact replica of jax.random.uniform(jax.random.key(42), (2048,2048)) at flat index f.
// JAX random_bits: counts = iota(N*N); x0 = counts[:H], x1 = counts[H:], H = N*N/2;
// out = concat(threefry2x32(key, x0, x1)).  key(42) -> (0, 42).
__device__ float threefry_uniform(unsigned int f) {
    const unsigned int H = (unsigned int)(N) * (unsigned int)(N) / 2u;
    unsigned int x0, x1; int word;
    if (f < H) { x0 = f;     x1 = f + H; word = 0; }
    else       { x0 = f - H; x1 = f;     word = 1; }
    unsigned int ks[3];
    ks[0] = 0u; ks[1] = 42u; ks[2] = 0u ^ 42u ^ 0x1BD11BDAu;
    x0 += ks[0]; x1 += ks[1];
    const int rotA[4] = {13, 15, 26, 6};
    const int rotB[4] = {17, 29, 16, 24};
    #pragma unroll
    for (int i = 0; i < 5; ++i) {
        const int* r = (i & 1) ? rotB : rotA;
        #pragma unroll
        for (int j = 0; j < 4; ++j) {
            x0 += x1; x1 = rotl32(x1, r[j]); x1 ^= x0;
        }
        x0 += ks[(i + 1) % 3];
        x1 += ks[(i + 2) % 3] + (unsigned int)(i + 1);
    }
    unsigned int bits = (word == 0) ? x0 : x1;
    return __uint_as_float((bits >> 9) | 0x3f800000u) - 1.0f;
}

// Kernel A: per-row ||x||^2 (fp32 exact), center-loss partial, fp32->bf16 convert.
__global__ void __launch_bounds__(256) prep_kernel(
        const float* __restrict__ emb, const int* __restrict__ labels,
        const float* __restrict__ centers, unsigned short* __restrict__ xbf,
        float* __restrict__ sq, float* __restrict__ centerp) {
    int i = blockIdx.x;
    int t = threadIdx.x;
    int lab = labels[i];
    const float4* erow = (const float4*)(emb + (size_t)i * FEAT);
    const float4* crow = (const float4*)(centers + (size_t)lab * FEAT);
    uint2* xrow = (uint2*)(xbf + (size_t)i * FEAT);
    float ssum = 0.f, csum = 0.f;
    #pragma unroll
    for (int p = 0; p < 2; ++p) {
        int idx4 = p * 256 + t;            // float4 index within row
        float4 e = erow[idx4];
        float4 c = crow[idx4];
        ssum += e.x*e.x + e.y*e.y + e.z*e.z + e.w*e.w;
        float dx = e.x-c.x, dy = e.y-c.y, dz = e.z-c.z, dw = e.w-c.w;
        csum += dx*dx + dy*dy + dz*dz + dw*dw;
        unsigned int w0 = (unsigned int)f32_to_bf16(e.x) | ((unsigned int)f32_to_bf16(e.y) << 16);
        unsigned int w1 = (unsigned int)f32_to_bf16(e.z) | ((unsigned int)f32_to_bf16(e.w) << 16);
        xrow[idx4] = make_uint2(w0, w1);
    }
    #pragma unroll
    for (int off = 32; off; off >>= 1) {
        ssum += __shfl_xor(ssum, off);
        csum += __shfl_xor(csum, off);
    }
    __shared__ float s1[4], s2[4];
    int lane = t & 63, w = t >> 6;
    if (lane == 0) { s1[w] = ssum; s2[w] = csum; }
    __syncthreads();
    if (t == 0) {
        sq[i]      = s1[0] + s1[1] + s1[2] + s1[3];
        centerp[i] = s2[0] + s2[1] + s2[2] + s2[3];
    }
}

// Kernel B: G = X X^T via bf16 MFMA; epilogue dist = sqrt(max(sq_i+sq_j-2g, 1e-12)).
// 128x128 tile, BK=32, 4 waves each computing a 64x64 quadrant (4x4 frags of 16x16).
__global__ void __launch_bounds__(256) gemm_dist_kernel(
        const unsigned short* __restrict__ xbf, const float* __restrict__ sq,
        float* __restrict__ dist) {
    __shared__ __align__(16) unsigned short As[128 * 32];
    __shared__ __align__(16) unsigned short Bs[128 * 32];
    int brow0 = blockIdx.y * 128;
    int bcol0 = blockIdx.x * 128;
    int t = threadIdx.x;
    int lane = t & 63, wid = t >> 6;
    int wr = wid >> 1, wc = wid & 1;
    f32x4 acc[4][4] = {};

    for (int kt = 0; kt < FEAT; kt += 32) {
        __syncthreads();
        #pragma unroll
        for (int p = 0; p < 2; ++p) {
            int flat = p * 256 + t;        // 16B chunk id, 0..511
            int row = flat >> 2;           // 0..127
            int c16 = flat & 3;            // 0..3
            ((uint4*)As)[flat] = *(const uint4*)(xbf + (size_t)(brow0 + row) * FEAT + kt + c16 * 8);
            ((uint4*)Bs)[flat] = *(const uint4*)(xbf + (size_t)(bcol0 + row) * FEAT + kt + c16 * 8);
        }
        __syncthreads();
        bf16x8 a[4], b[4];
        #pragma unroll
        for (int m = 0; m < 4; ++m)
            a[m] = *(const bf16x8*)(&As[(wr * 64 + m * 16 + (lane & 15)) * 32 + (lane >> 4) * 8]);
        #pragma unroll
        for (int n = 0; n < 4; ++n)
            b[n] = *(const bf16x8*)(&Bs[(wc * 64 + n * 16 + (lane & 15)) * 32 + (lane >> 4) * 8]);
        #pragma unroll
        for (int m = 0; m < 4; ++m)
            #pragma unroll
            for (int n = 0; n < 4; ++n)
                acc[m][n] = __builtin_amdgcn_mfma_f32_16x16x32_bf16(a[m], b[n], acc[m][n], 0, 0, 0);
    }

    // Epilogue: C/D layout col = lane&15, row = (lane>>4)*4 + reg  [measured m89/m91]
    #pragma unroll
    for (int m = 0; m < 4; ++m) {
        int grow_base = brow0 + wr * 64 + m * 16 + (lane >> 4) * 4;
        #pragma unroll
        for (int n = 0; n < 4; ++n) {
            int gcol = bcol0 + wc * 64 + n * 16 + (lane & 15);
            float sqc = sq[gcol];
            #pragma unroll
            for (int r = 0; r < 4; ++r) {
                int grow = grow_base + r;
                float d2 = sq[grow] + sqc - 2.0f * acc[m][n][r];
                dist[(size_t)grow * N + gcol] = sqrtf(fmaxf(d2, 1e-12f));
            }
        }
    }
}

// Kernel C: per-row top-10 smallest negative distances + exact threefry positive pick.
__global__ void __launch_bounds__(256) topk_kernel(
        const float* __restrict__ dist, const int* __restrict__ labels,
        float* __restrict__ d_ap, int* __restrict__ avalid,
        int* __restrict__ negs1, float* __restrict__ d_an) {
    int i = blockIdx.x;
    int t = threadIdx.x;
    int lab = labels[i];
    const float INF = __int_as_float(0x7f800000);
    __shared__ float vals[N];
    __shared__ float rv[256];
    __shared__ int   ri[256];
    __shared__ int   rc[256];

    float bestu = -1.0f; int bestj = 0;
    int negc = 0;
    for (int j = t; j < N; j += 256) {
        int lj = labels[j];
        float d = dist[(size_t)i * N + j];
        if (lj == lab) {
            vals[j] = INF;
            if (j != i) {
                float u = threefry_uniform((unsigned int)(i * N + j));
                if (u > bestu || (u == bestu && j < bestj)) { bestu = u; bestj = j; }
            }
        } else {
            vals[j] = d;
            negc++;
        }
    }
    rv[t] = bestu; ri[t] = bestj; rc[t] = negc;
    __syncthreads();
    for (int s = 128; s > 0; s >>= 1) {
        if (t < s) {
            if (rv[t + s] > rv[t] || (rv[t + s] == rv[t] && ri[t + s] < ri[t])) {
                rv[t] = rv[t + s]; ri[t] = ri[t + s];
            }
            rc[t] += rc[t + s];
        }
        __syncthreads();
    }
    float bu = rv[0]; int bj = ri[0]; int nc = rc[0];
    __syncthreads();

    // 10 argmin passes (first-index tie-break matches lax.top_k stability)
    for (int q = 0; q < K_NEG; ++q) {
        float mv = INF; int mi = N;
        for (int j = t; j < N; j += 256) {
            float v = vals[j];
            if (v < mv || (v == mv && j < mi)) { mv = v; mi = j; }
        }
        rv[t] = mv; ri[t] = mi;
        __syncthreads();
        for (int s = 128; s > 0; s >>= 1) {
            if (t < s) {
                if (rv[t + s] < rv[t] || (rv[t + s] == rv[t] && ri[t + s] < ri[t])) {
                    rv[t] = rv[t + s]; ri[t] = ri[t + s];
                }
            }
            __syncthreads();
        }
        if (t == 0) {
            negs1[i * K_NEG + q] = ri[0];
            d_an[i * K_NEG + q]  = rv[0];
            if (ri[0] < N) vals[ri[0]] = INF;
        }
        __syncthreads();
    }
    if (t == 0) {
        bool has_pos = (bu >= 0.0f);
        avalid[i] = (has_pos && nc >= 2) ? 1 : 0;
        d_ap[i]   = has_pos ? dist[(size_t)i * N + bj] : 0.0f;
    }
}

// Kernel D: per (i,k): d_n1n2 = min_j dist[n1][j] over labels[j]!=labels[i], j!=n1.
// One wave per task; fused term computation.
__global__ void __launch_bounds__(256) neg2_kernel(
        const float* __restrict__ dist, const int* __restrict__ labels,
        const int* __restrict__ negs1, const float* __restrict__ d_an,
        const float* __restrict__ d_ap, const int* __restrict__ avalid,
        float* __restrict__ terms, float* __restrict__ validf) {
    int task = blockIdx.x * 4 + (threadIdx.x >> 6);
    int lane = threadIdx.x & 63;
    int i = task / K_NEG;
    int n1 = negs1[task];
    int lab = labels[i];
    const float INF = __int_as_float(0x7f800000);
    const float* row = dist + (size_t)n1 * N;
    float m = INF;
    for (int j = lane; j < N; j += 64) {
        float d = row[j];
        bool ok = (labels[j] != lab) && (j != n1);
        m = ok ? fminf(m, d) : m;
    }
    #pragma unroll
    for (int off = 32; off; off >>= 1) m = fminf(m, __shfl_xor(m, off));
    if (lane == 0) {
        float dan = d_an[task];
        float dap = d_ap[i];
        float t1 = fmaxf(dap - dan + M1, 0.0f);
        float t2 = fmaxf(dap - m   + M2, 0.0f);
        bool valid = (avalid[i] != 0) && (dan < INF) && (m < INF);
        terms[task]  = valid ? (t1 + t2) : 0.0f;
        validf[task] = valid ? 1.0f : 0.0f;
    }
}

// Kernel E: deterministic final reduction.
__global__ void __launch_bounds__(256) finalize_kernel(
        const float* __restrict__ terms, const float* __restrict__ validf,
        const float* __restrict__ centerp, float* __restrict__ out) {
    int t = threadIdx.x;
    float ts = 0.f, vs = 0.f, cs = 0.f;
    for (int j = t; j < N * K_NEG; j += 256) { ts += terms[j]; vs += validf[j]; }
    for (int j = t; j < N; j += 256) cs += centerp[j];
    __shared__ float a[256], b[256], c[256];
    a[t] = ts; b[t] = vs; c[t] = cs;
    __syncthreads();
    for (int s = 128; s > 0; s >>= 1) {
        if (t < s) { a[t] += a[t + s]; b[t] += b[t + s]; c[t] += c[t + s]; }
        __syncthreads();
    }
    if (t == 0) {
        float quad = (b[0] > 0.0f) ? (a[0] / b[0]) : 0.0f;
        out[0] = quad + CW * (c[0] / (float)N);
    }
}

extern "C" void kernel_launch(void* const* d_in, const int* in_sizes, int n_in,
                              void* d_out, int out_size, void* d_ws, size_t ws_size,
                              hipStream_t stream) {
    const float* emb     = (const float*)d_in[0];
    const int*   labels  = (const int*)d_in[1];
    const float* centers = (const float*)d_in[2];
    float* out = (float*)d_out;

    char* ws = (char*)d_ws;
    unsigned short* xbf = (unsigned short*)ws;                 // 8 MB
    float* dist = (float*)(ws + (size_t)8 * 1024 * 1024);      // 16 MB
    char* p = ws + (size_t)24 * 1024 * 1024;
    float* sq      = (float*)p; p += N * 4;
    float* centerp = (float*)p; p += N * 4;
    float* d_ap    = (float*)p; p += N * 4;
    int*   avalid  = (int*)p;   p += N * 4;
    int*   negs1   = (int*)p;   p += N * K_NEG * 4;
    float* d_an    = (float*)p; p += N * K_NEG * 4;
    float* terms   = (float*)p; p += N * K_NEG * 4;
    float* validf  = (float*)p; p += N * K_NEG * 4;

    prep_kernel<<<N, 256, 0, stream>>>(emb, labels, centers, xbf, sq, centerp);
    dim3 g(N / 128, N / 128);
    gemm_dist_kernel<<<g, 256, 0, stream>>>(xbf, sq, dist);
    topk_kernel<<<N, 256, 0, stream>>>(dist, labels, d_ap, avalid, negs1, d_an);
    neg2_kernel<<<(N * K_NEG) / 4, 256, 0, stream>>>(dist, labels, negs1, d_an, d_ap, avalid, terms, validf);
    finalize_kernel<<<1, 256, 0, stream>>>(terms, validf, centerp, out);
}

// Round 2
// 122.435 us; speedup vs baseline: 1.4603x; 1.4603x over previous
//
#include <hip/hip_runtime.h>
#include <hip/hip_bf16.h>

#define N 2048
#define FEAT 2048
#define K_NEG 10
#define NCLS 288
#define M1 0.3f
#define M2 0.3f
#define CW 0.01f

typedef __attribute__((ext_vector_type(8))) __bf16 bf16x8;
typedef __attribute__((ext_vector_type(4))) float f32x4;

__device__ __forceinline__ unsigned short f32_to_bf16(float f) {
    unsigned int u = __float_as_uint(f);
    u += 0x7fffu + ((u >> 16) & 1u);   // round-to-nearest-even
    return (unsigned short)(u >> 16);
}

__device__ __forceinline__ unsigned int rotl32(unsigned int x, int d) {
    return (x << d) | (x >> (32 - d));
}

// Exact replica of jax.random.uniform(jax.random.key(42), (2048,2048)) at flat index f.
__device__ float threefry_uniform(unsigned int f) {
    const unsigned int H = (unsigned int)(N) * (unsigned int)(N) / 2u;
    unsigned int x0, x1; int word;
    if (f < H) { x0 = f;     x1 = f + H; word = 0; }
    else       { x0 = f - H; x1 = f;     word = 1; }
    unsigned int ks[3];
    ks[0] = 0u; ks[1] = 42u; ks[2] = 0u ^ 42u ^ 0x1BD11BDAu;
    x0 += ks[0]; x1 += ks[1];
    const int rotA[4] = {13, 15, 26, 6};
    const int rotB[4] = {17, 29, 16, 24};
    #pragma unroll
    for (int i = 0; i < 5; ++i) {
        const int* r = (i & 1) ? rotB : rotA;
        #pragma unroll
        for (int j = 0; j < 4; ++j) {
            x0 += x1; x1 = rotl32(x1, r[j]); x1 ^= x0;
        }
        x0 += ks[(i + 1) % 3];
        x1 += ks[(i + 2) % 3] + (unsigned int)(i + 1);
    }
    unsigned int bits = (word == 0) ? x0 : x1;
    return __uint_as_float((bits >> 9) | 0x3f800000u) - 1.0f;
}

// Kernel A: per-row ||x||^2 (fp32 exact), center-loss partial, fp32->bf16 convert.
__global__ void __launch_bounds__(256) prep_kernel(
        const float* __restrict__ emb, const int* __restrict__ labels,
        const float* __restrict__ centers, unsigned short* __restrict__ xbf,
        float* __restrict__ sq, float* __restrict__ centerp) {
    int i = blockIdx.x;
    int t = threadIdx.x;
    int lab = labels[i];
    const float4* erow = (const float4*)(emb + (size_t)i * FEAT);
    const float4* crow = (const float4*)(centers + (size_t)lab * FEAT);
    uint2* xrow = (uint2*)(xbf + (size_t)i * FEAT);
    float ssum = 0.f, csum = 0.f;
    #pragma unroll
    for (int p = 0; p < 2; ++p) {
        int idx4 = p * 256 + t;
        float4 e = erow[idx4];
        float4 c = crow[idx4];
        ssum += e.x*e.x + e.y*e.y + e.z*e.z + e.w*e.w;
        float dx = e.x-c.x, dy = e.y-c.y, dz = e.z-c.z, dw = e.w-c.w;
        csum += dx*dx + dy*dy + dz*dz + dw*dw;
        unsigned int w0 = (unsigned int)f32_to_bf16(e.x) | ((unsigned int)f32_to_bf16(e.y) << 16);
        unsigned int w1 = (unsigned int)f32_to_bf16(e.z) | ((unsigned int)f32_to_bf16(e.w) << 16);
        xrow[idx4] = make_uint2(w0, w1);
    }
    #pragma unroll
    for (int off = 32; off; off >>= 1) {
        ssum += __shfl_xor(ssum, off);
        csum += __shfl_xor(csum, off);
    }
    __shared__ float s1[4], s2[4];
    int lane = t & 63, w = t >> 6;
    if (lane == 0) { s1[w] = ssum; s2[w] = csum; }
    __syncthreads();
    if (t == 0) {
        sq[i]      = s1[0] + s1[1] + s1[2] + s1[3];
        centerp[i] = s2[0] + s2[1] + s2[2] + s2[3];
    }
}

// Kernel B: G = X X^T via bf16 MFMA; epilogue dist = sqrt(max(sq_i+sq_j-2g, 1e-12)).
__global__ void __launch_bounds__(256) gemm_dist_kernel(
        const unsigned short* __restrict__ xbf, const float* __restrict__ sq,
        float* __restrict__ dist) {
    __shared__ __align__(16) unsigned short As[128 * 32];
    __shared__ __align__(16) unsigned short Bs[128 * 32];
    int brow0 = blockIdx.y * 128;
    int bcol0 = blockIdx.x * 128;
    int t = threadIdx.x;
    int lane = t & 63, wid = t >> 6;
    int wr = wid >> 1, wc = wid & 1;
    f32x4 acc[4][4] = {};

    for (int kt = 0; kt < FEAT; kt += 32) {
        __syncthreads();
        #pragma unroll
        for (int p = 0; p < 2; ++p) {
            int flat = p * 256 + t;
            int row = flat >> 2;
            int c16 = flat & 3;
            ((uint4*)As)[flat] = *(const uint4*)(xbf + (size_t)(brow0 + row) * FEAT + kt + c16 * 8);
            ((uint4*)Bs)[flat] = *(const uint4*)(xbf + (size_t)(bcol0 + row) * FEAT + kt + c16 * 8);
        }
        __syncthreads();
        bf16x8 a[4], b[4];
        #pragma unroll
        for (int m = 0; m < 4; ++m)
            a[m] = *(const bf16x8*)(&As[(wr * 64 + m * 16 + (lane & 15)) * 32 + (lane >> 4) * 8]);
        #pragma unroll
        for (int n = 0; n < 4; ++n)
            b[n] = *(const bf16x8*)(&Bs[(wc * 64 + n * 16 + (lane & 15)) * 32 + (lane >> 4) * 8]);
        #pragma unroll
        for (int m = 0; m < 4; ++m)
            #pragma unroll
            for (int n = 0; n < 4; ++n)
                acc[m][n] = __builtin_amdgcn_mfma_f32_16x16x32_bf16(a[m], b[n], acc[m][n], 0, 0, 0);
    }

    #pragma unroll
    for (int m = 0; m < 4; ++m) {
        int grow_base = brow0 + wr * 64 + m * 16 + (lane >> 4) * 4;
        #pragma unroll
        for (int n = 0; n < 4; ++n) {
            int gcol = bcol0 + wc * 64 + n * 16 + (lane & 15);
            float sqc = sq[gcol];
            #pragma unroll
            for (int r = 0; r < 4; ++r) {
                int grow = grow_base + r;
                float d2 = sq[grow] + sqc - 2.0f * acc[m][n][r];
                dist[(size_t)grow * N + gcol] = sqrtf(fmaxf(d2, 1e-12f));
            }
        }
    }
}

// Kernel C: per-row top-10 negatives + threefry positive pick + per-row per-class
// minima (min1, argmin class, min2) for the neg2 stage.
__global__ void __launch_bounds__(256) topk_kernel(
        const float* __restrict__ dist, const int* __restrict__ labels,
        float* __restrict__ d_ap, int* __restrict__ avalid,
        int* __restrict__ negs1, float* __restrict__ d_an,
        float* __restrict__ rmin1, int* __restrict__ rc1, float* __restrict__ rmin2) {
    int i = blockIdx.x;
    int t = threadIdx.x;
    int lab = labels[i];
    const float INF = __int_as_float(0x7f800000);
    __shared__ float vals[N];
    __shared__ float rv[256];
    __shared__ int   ri[256];
    __shared__ int   rc[256];
    __shared__ float rm2[256];
    __shared__ unsigned int mbuck[NCLS];

    for (int c = t; c < NCLS; c += 256) mbuck[c] = 0x7f800000u;
    __syncthreads();

    float bestu = -1.0f; int bestj = 0;
    int negc = 0;
    for (int j = t; j < N; j += 256) {
        int lj = labels[j];
        float d = dist[(size_t)i * N + j];
        if (j != i) atomicMin(&mbuck[lj], __float_as_uint(d));
        if (lj == lab) {
            vals[j] = INF;
            if (j != i) {
                float u = threefry_uniform((unsigned int)(i * N + j));
                if (u > bestu || (u == bestu && j < bestj)) { bestu = u; bestj = j; }
            }
        } else {
            vals[j] = d;
            negc++;
        }
    }
    rv[t] = bestu; ri[t] = bestj; rc[t] = negc;
    __syncthreads();
    for (int s = 128; s > 0; s >>= 1) {
        if (t < s) {
            if (rv[t + s] > rv[t] || (rv[t + s] == rv[t] && ri[t + s] < ri[t])) {
                rv[t] = rv[t + s]; ri[t] = ri[t + s];
            }
            rc[t] += rc[t + s];
        }
        __syncthreads();
    }
    float bu = rv[0]; int bj = ri[0]; int nc = rc[0];
    __syncthreads();

    // 10 argmin passes (first-index tie-break matches lax.top_k stability)
    for (int q = 0; q < K_NEG; ++q) {
        float mv = INF; int mi = N;
        for (int j = t; j < N; j += 256) {
            float v = vals[j];
            if (v < mv || (v == mv && j < mi)) { mv = v; mi = j; }
        }
        rv[t] = mv; ri[t] = mi;
        __syncthreads();
        for (int s = 128; s > 0; s >>= 1) {
            if (t < s) {
                if (rv[t + s] < rv[t] || (rv[t + s] == rv[t] && ri[t + s] < ri[t])) {
                    rv[t] = rv[t + s]; ri[t] = ri[t + s];
                }
            }
            __syncthreads();
        }
        if (t == 0) {
            negs1[i * K_NEG + q] = ri[0];
            d_an[i * K_NEG + q]  = rv[0];
            if (ri[0] < N) vals[ri[0]] = INF;
        }
        __syncthreads();
    }
    if (t == 0) {
        bool has_pos = (bu >= 0.0f);
        avalid[i] = (has_pos && nc >= 2) ? 1 : 0;
        d_ap[i]   = has_pos ? dist[(size_t)i * N + bj] : 0.0f;
    }
    __syncthreads();

    // (min1, argmin-class, min2) over the 288 class buckets.
    {
        float a1 = __uint_as_float(mbuck[t]);
        int   ac = t;
        float b1 = (t < NCLS - 256) ? __uint_as_float(mbuck[256 + t]) : INF;
        int   bc = 256 + t;
        float m1v, m2v; int c1v;
        if (a1 <= b1) { m1v = a1; c1v = ac; m2v = b1; }
        else          { m1v = b1; c1v = bc; m2v = a1; }
        rv[t] = m1v; ri[t] = c1v; rm2[t] = m2v;
        __syncthreads();
        for (int s = 128; s > 0; s >>= 1) {
            if (t < s) {
                float o1 = rv[t + s]; int oc = ri[t + s]; float o2 = rm2[t + s];
                float c1m = rv[t];
                if (o1 < c1m) { rv[t] = o1; ri[t] = oc; rm2[t] = fminf(o2, c1m); }
                else          { rm2[t] = fminf(rm2[t], o1); }
            }
            __syncthreads();
        }
        if (t == 0) { rmin1[i] = rv[0]; rc1[i] = ri[0]; rmin2[i] = rm2[0]; }
    }
}

// Kernel D (cheap): per-task term from cached per-row class minima.
__global__ void __launch_bounds__(256) terms_kernel(
        const int* __restrict__ labels, const int* __restrict__ negs1,
        const float* __restrict__ d_an, const float* __restrict__ d_ap,
        const int* __restrict__ avalid, const float* __restrict__ rmin1,
        const int* __restrict__ rc1, const float* __restrict__ rmin2,
        float* __restrict__ terms, float* __restrict__ validf) {
    int task = blockIdx.x * 256 + threadIdx.x;
    if (task >= N * K_NEG) return;
    int i = task / K_NEG;
    int n1 = negs1[task];
    int lab = labels[i];
    const float INF = __int_as_float(0x7f800000);
    float dn2 = (rc1[n1] == lab) ? rmin2[n1] : rmin1[n1];
    float dan = d_an[task];
    float dap = d_ap[i];
    float t1 = fmaxf(dap - dan + M1, 0.0f);
    float t2 = fmaxf(dap - dn2 + M2, 0.0f);
    bool valid = (avalid[i] != 0) && (dan < INF) && (dn2 < INF);
    terms[task]  = valid ? (t1 + t2) : 0.0f;
    validf[task] = valid ? 1.0f : 0.0f;
}

// Kernel E: deterministic final reduction.
__global__ void __launch_bounds__(256) finalize_kernel(
        const float* __restrict__ terms, const float* __restrict__ validf,
        const float* __restrict__ centerp, float* __restrict__ out) {
    int t = threadIdx.x;
    float ts = 0.f, vs = 0.f, cs = 0.f;
    for (int j = t; j < N * K_NEG; j += 256) { ts += terms[j]; vs += validf[j]; }
    for (int j = t; j < N; j += 256) cs += centerp[j];
    __shared__ float a[256], b[256], c[256];
    a[t] = ts; b[t] = vs; c[t] = cs;
    __syncthreads();
    for (int s = 128; s > 0; s >>= 1) {
        if (t < s) { a[t] += a[t + s]; b[t] += b[t + s]; c[t] += c[t + s]; }
        __syncthreads();
    }
    if (t == 0) {
        float quad = (b[0] > 0.0f) ? (a[0] / b[0]) : 0.0f;
        out[0] = quad + CW * (c[0] / (float)N);
    }
}

extern "C" void kernel_launch(void* const* d_in, const int* in_sizes, int n_in,
                              void* d_out, int out_size, void* d_ws, size_t ws_size,
                              hipStream_t stream) {
    const float* emb     = (const float*)d_in[0];
    const int*   labels  = (const int*)d_in[1];
    const float* centers = (const float*)d_in[2];
    float* out = (float*)d_out;

    char* ws = (char*)d_ws;
    unsigned short* xbf = (unsigned short*)ws;                 // 8 MB
    float* dist = (float*)(ws + (size_t)8 * 1024 * 1024);      // 16 MB
    char* p = ws + (size_t)24 * 1024 * 1024;
    float* sq      = (float*)p; p += N * 4;
    float* centerp = (float*)p; p += N * 4;
    float* d_ap    = (float*)p; p += N * 4;
    int*   avalid  = (int*)p;   p += N * 4;
    float* rmin1   = (float*)p; p += N * 4;
    int*   rc1     = (int*)p;   p += N * 4;
    float* rmin2   = (float*)p; p += N * 4;
    int*   negs1   = (int*)p;   p += N * K_NEG * 4;
    float* d_an    = (float*)p; p += N * K_NEG * 4;
    float* terms   = (float*)p; p += N * K_NEG * 4;
    float* validf  = (float*)p; p += N * K_NEG * 4;

    prep_kernel<<<N, 256, 0, stream>>>(emb, labels, centers, xbf, sq, centerp);
    dim3 g(N / 128, N / 128);
    gemm_dist_kernel<<<g, 256, 0, stream>>>(xbf, sq, dist);
    topk_kernel<<<N, 256, 0, stream>>>(dist, labels, d_ap, avalid, negs1, d_an,
                                       rmin1, rc1, rmin2);
    terms_kernel<<<(N * K_NEG + 255) / 256, 256, 0, stream>>>(
        labels, negs1, d_an, d_ap, avalid, rmin1, rc1, rmin2, terms, validf);
    finalize_kernel<<<1, 256, 0, stream>>>(terms, validf, centerp, out);
}

// Round 3
// 110.499 us; speedup vs baseline: 1.6180x; 1.1080x over previous
//
#include <hip/hip_runtime.h>
#include <hip/hip_bf16.h>

#define N 2048
#define FEAT 2048
#define K_NEG 10
#define NCLS 288
#define M1 0.3f
#define M2 0.3f
#define CW 0.01f

#define BM 128
#define BN 128
#define BK 64
#define NT (FEAT / BK)

typedef __attribute__((ext_vector_type(8))) __bf16 bf16x8;
typedef __attribute__((ext_vector_type(4))) float f32x4;
typedef unsigned long long u64;

__device__ __forceinline__ unsigned short f32_to_bf16(float f) {
    unsigned int u = __float_as_uint(f);
    u += 0x7fffu + ((u >> 16) & 1u);   // round-to-nearest-even
    return (unsigned short)(u >> 16);
}

__device__ __forceinline__ unsigned int rotl32(unsigned int x, int d) {
    return (x << d) | (x >> (32 - d));
}

// Exact replica of jax.random.uniform(jax.random.key(42), (2048,2048)) at flat index f.
__device__ float threefry_uniform(unsigned int f) {
    const unsigned int H = (unsigned int)(N) * (unsigned int)(N) / 2u;
    unsigned int x0, x1; int word;
    if (f < H) { x0 = f;     x1 = f + H; word = 0; }
    else       { x0 = f - H; x1 = f;     word = 1; }
    unsigned int ks[3];
    ks[0] = 0u; ks[1] = 42u; ks[2] = 0u ^ 42u ^ 0x1BD11BDAu;
    x0 += ks[0]; x1 += ks[1];
    const int rotA[4] = {13, 15, 26, 6};
    const int rotB[4] = {17, 29, 16, 24};
    #pragma unroll
    for (int i = 0; i < 5; ++i) {
        const int* r = (i & 1) ? rotB : rotA;
        #pragma unroll
        for (int j = 0; j < 4; ++j) {
            x0 += x1; x1 = rotl32(x1, r[j]); x1 ^= x0;
        }
        x0 += ks[(i + 1) % 3];
        x1 += ks[(i + 2) % 3] + (unsigned int)(i + 1);
    }
    unsigned int bits = (word == 0) ? x0 : x1;
    return __uint_as_float((bits >> 9) | 0x3f800000u) - 1.0f;
}

// async 16B global -> LDS (linear dest = wave-uniform base + lane*16)
__device__ __forceinline__ void gld16(const unsigned short* g, unsigned short* l) {
    __builtin_amdgcn_global_load_lds(
        (const __attribute__((address_space(1))) unsigned int*)g,
        (__attribute__((address_space(3))) unsigned int*)l,
        16, 0, 0);
}

// Kernel A: per-row ||x||^2 (fp32 exact), center-loss partial, fp32->bf16 convert.
__global__ void __launch_bounds__(256) prep_kernel(
        const float* __restrict__ emb, const int* __restrict__ labels,
        const float* __restrict__ centers, unsigned short* __restrict__ xbf,
        float* __restrict__ sq, float* __restrict__ centerp) {
    int i = blockIdx.x;
    int t = threadIdx.x;
    int lab = labels[i];
    const float4* erow = (const float4*)(emb + (size_t)i * FEAT);
    const float4* crow = (const float4*)(centers + (size_t)lab * FEAT);
    uint2* xrow = (uint2*)(xbf + (size_t)i * FEAT);
    float ssum = 0.f, csum = 0.f;
    #pragma unroll
    for (int p = 0; p < 2; ++p) {
        int idx4 = p * 256 + t;
        float4 e = erow[idx4];
        float4 c = crow[idx4];
        ssum += e.x*e.x + e.y*e.y + e.z*e.z + e.w*e.w;
        float dx = e.x-c.x, dy = e.y-c.y, dz = e.z-c.z, dw = e.w-c.w;
        csum += dx*dx + dy*dy + dz*dz + dw*dw;
        unsigned int w0 = (unsigned int)f32_to_bf16(e.x) | ((unsigned int)f32_to_bf16(e.y) << 16);
        unsigned int w1 = (unsigned int)f32_to_bf16(e.z) | ((unsigned int)f32_to_bf16(e.w) << 16);
        xrow[idx4] = make_uint2(w0, w1);
    }
    #pragma unroll
    for (int off = 32; off; off >>= 1) {
        ssum += __shfl_xor(ssum, off);
        csum += __shfl_xor(csum, off);
    }
    __shared__ float s1[4], s2[4];
    int lane = t & 63, w = t >> 6;
    if (lane == 0) { s1[w] = ssum; s2[w] = csum; }
    __syncthreads();
    if (t == 0) {
        sq[i]      = s1[0] + s1[1] + s1[2] + s1[3];
        centerp[i] = s2[0] + s2[1] + s2[2] + s2[3];
    }
}

// Kernel B: G = X X^T via bf16 MFMA, 2-phase pipelined (T3 minimum recipe).
// 128x128 tile, BK=64, 512 threads = 8 waves (2x4), each wave 64x32 output.
// global_load_lds width-16 into double-buffered LDS; vmcnt(0)+barrier once per K-step.
__global__ void __launch_bounds__(512) gemm_dist_kernel(
        const unsigned short* __restrict__ xbf, const float* __restrict__ sq,
        float* __restrict__ dist) {
    __shared__ __align__(16) unsigned short As[2][BM * BK];
    __shared__ __align__(16) unsigned short Bs[2][BM * BK];
    int brow0 = blockIdx.y * BM;
    int bcol0 = blockIdx.x * BN;
    int t = threadIdx.x;
    int lane = t & 63, wid = t >> 6;
    int wr = wid >> 2, wc = wid & 3;          // 2 x 4 wave grid
    f32x4 acc[4][2] = {};

    // stage one K-tile (A+B) into buffer `buf`; 1024 16B-chunks each, 2 per thread
    #define STAGE(buf, kelem) do {                                              \
        _Pragma("unroll")                                                       \
        for (int q = 0; q < 2; ++q) {                                           \
            int chunk = q * 512 + t;                                            \
            int row = chunk >> 3, c16 = chunk & 7;  /* 8 chunks per 64-col row */ \
            gld16(xbf + (size_t)(brow0 + row) * FEAT + (kelem) + c16 * 8,       \
                  &As[buf][chunk * 8]);                                         \
            gld16(xbf + (size_t)(bcol0 + row) * FEAT + (kelem) + c16 * 8,       \
                  &Bs[buf][chunk * 8]);                                         \
        } } while (0)

    STAGE(0, 0);
    asm volatile("s_waitcnt vmcnt(0)" ::: "memory");
    __syncthreads();

    for (int kt = 0; kt < NT; ++kt) {
        int cur = kt & 1;
        if (kt + 1 < NT) STAGE(cur ^ 1, (kt + 1) * BK);

        bf16x8 a[2][4], b[2][2];
        #pragma unroll
        for (int kk = 0; kk < 2; ++kk) {
            #pragma unroll
            for (int m = 0; m < 4; ++m)
                a[kk][m] = *(const bf16x8*)(&As[cur][(wr * 64 + m * 16 + (lane & 15)) * BK + kk * 32 + (lane >> 4) * 8]);
            #pragma unroll
            for (int n = 0; n < 2; ++n)
                b[kk][n] = *(const bf16x8*)(&Bs[cur][(wc * 32 + n * 16 + (lane & 15)) * BK + kk * 32 + (lane >> 4) * 8]);
        }
        #pragma unroll
        for (int m = 0; m < 4; ++m)
            #pragma unroll
            for (int n = 0; n < 2; ++n)
                #pragma unroll
                for (int kk = 0; kk < 2; ++kk)
                    acc[m][n] = __builtin_amdgcn_mfma_f32_16x16x32_bf16(a[kk][m], b[kk][n], acc[m][n], 0, 0, 0);

        asm volatile("s_waitcnt vmcnt(0)" ::: "memory");
        __syncthreads();
    }
    #undef STAGE

    // C/D layout: col = lane&15, row = (lane>>4)*4 + reg  [m89/m91]
    #pragma unroll
    for (int m = 0; m < 4; ++m) {
        int grow_base = brow0 + wr * 64 + m * 16 + (lane >> 4) * 4;
        #pragma unroll
        for (int n = 0; n < 2; ++n) {
            int gcol = bcol0 + wc * 32 + n * 16 + (lane & 15);
            float sqc = sq[gcol];
            #pragma unroll
            for (int r = 0; r < 4; ++r) {
                int grow = grow_base + r;
                float d2 = sq[grow] + sqc - 2.0f * acc[m][n][r];
                dist[(size_t)grow * N + gcol] = sqrtf(fmaxf(d2, 1e-12f));
            }
        }
    }
}

// Kernel C: per-row top-10 negatives via u64-key sort+merge tree, threefry positive
// pick, and per-row per-class minima (min1, argmin class, min2) for neg2.
// key = (float_bits(dist) << 32) | idx  -> ascending u64 order == (dist asc, idx asc).
__global__ void __launch_bounds__(256) topk_kernel(
        const float* __restrict__ dist, const int* __restrict__ labels,
        float* __restrict__ d_ap, int* __restrict__ avalid,
        int* __restrict__ negs1, float* __restrict__ d_an,
        float* __restrict__ rmin1, int* __restrict__ rc1, float* __restrict__ rmin2) {
    int i = blockIdx.x;
    int t = threadIdx.x;
    int lab = labels[i];
    const float INF = __int_as_float(0x7f800000);
    const u64 PADKEY = 0xFFFFFFFFFFFFFFFFull;

    __shared__ u64 lb0[256 * K_NEG];
    __shared__ u64 lb1[128 * K_NEG];          // dst lists only for t < 128
    __shared__ unsigned int mbuck[NCLS];
    __shared__ float rv[256];
    __shared__ int   ri[256];
    __shared__ int   rc[256];
    __shared__ float rm2[256];

    for (int c = t; c < NCLS; c += 256) mbuck[c] = 0x7f800000u;
    __syncthreads();

    // Phase 1: strided scan; build 8 u64 keys; threefry best; neg count; class mins.
    u64 k[8];
    float bestu = -1.0f; int bestj = 0;
    int negc = 0;
    #pragma unroll
    for (int s = 0; s < 8; ++s) {
        int j = s * 256 + t;
        float d = dist[(size_t)i * N + j];
        int lj = labels[j];
        if (j != i) atomicMin(&mbuck[lj], __float_as_uint(d));
        if (lj == lab) {
            k[s] = PADKEY;
            if (j != i) {
                float u = threefry_uniform((unsigned int)(i * N + j));
                if (u > bestu || (u == bestu && j < bestj)) { bestu = u; bestj = j; }
            }
        } else {
            k[s] = ((u64)__float_as_uint(d) << 32) | (unsigned int)j;
            negc++;
        }
    }

    // 8-element Batcher odd-even sorting network (static indices).
    #define CE(x, y) { u64 lo = k[x] < k[y] ? k[x] : k[y]; u64 hi = k[x] < k[y] ? k[y] : k[x]; k[x] = lo; k[y] = hi; }
    CE(0,1) CE(2,3) CE(4,5) CE(6,7)
    CE(0,2) CE(1,3) CE(4,6) CE(5,7)
    CE(1,2) CE(5,6)
    CE(0,4) CE(1,5) CE(2,6) CE(3,7)
    CE(2,4) CE(3,5)
    CE(1,2) CE(3,4) CE(5,6)
    #undef CE

    #pragma unroll
    for (int q = 0; q < 8; ++q) lb0[t * K_NEG + q] = k[q];
    lb0[t * K_NEG + 8] = PADKEY;
    lb0[t * K_NEG + 9] = PADKEY;

    // reduce threefry best + neg count
    rv[t] = bestu; ri[t] = bestj; rc[t] = negc;
    __syncthreads();
    for (int s = 128; s > 0; s >>= 1) {
        if (t < s) {
            if (rv[t + s] > rv[t] || (rv[t + s] == rv[t] && ri[t + s] < ri[t])) {
                rv[t] = rv[t + s]; ri[t] = ri[t + s];
            }
            rc[t] += rc[t + s];
        }
        __syncthreads();
    }
    float bu = rv[0]; int bj = ri[0]; int nc = rc[0];

    // Phase 2: 8 ping-pong merge rounds; round r: src = (r even ? lb0 : lb1).
    #pragma unroll
    for (int r = 0; r < 8; ++r) {
        int s = 128 >> r;
        u64* src = (r & 1) ? lb1 : lb0;
        u64* dst = (r & 1) ? lb0 : lb1;
        if (t < s) {
            const u64* A = &src[t * K_NEG];
            const u64* B = &src[(t + s) * K_NEG];
            u64* D = &dst[t * K_NEG];
            int pa = 0, pb = 0;
            u64 ha = A[0], hb = B[0];
            #pragma unroll
            for (int q = 0; q < K_NEG; ++q) {
                bool ta = ha <= hb;
                D[q] = ta ? ha : hb;
                if (ta) { ++pa; ha = (pa < K_NEG) ? A[pa] : PADKEY; }
                else    { ++pb; hb = (pb < K_NEG) ? B[pb] : PADKEY; }
            }
        }
        __syncthreads();
    }
    // final list is in lb0 (round 7: src lb1 -> dst lb0), list 0
    if (t < K_NEG) {
        u64 key = lb0[t];
        unsigned int hv = (unsigned int)(key >> 32);
        bool fin = hv < 0x7f800000u;
        d_an[i * K_NEG + t]  = fin ? __uint_as_float(hv) : INF;
        negs1[i * K_NEG + t] = fin ? (int)(key & 0xFFFFFFFFu) : 0;
    }
    if (t == 0) {
        bool has_pos = (bu >= 0.0f);
        avalid[i] = (has_pos && nc >= 2) ? 1 : 0;
        d_ap[i]   = has_pos ? dist[(size_t)i * N + bj] : 0.0f;
    }
    __syncthreads();

    // Phase 3: (min1, argmin-class, min2) over the 288 class buckets.
    {
        float a1 = __uint_as_float(mbuck[t]);
        int   ac = t;
        float b1 = (t < NCLS - 256) ? __uint_as_float(mbuck[256 + t]) : INF;
        int   bc = 256 + t;
        float m1v, m2v; int c1v;
        if (a1 <= b1) { m1v = a1; c1v = ac; m2v = b1; }
        else          { m1v = b1; c1v = bc; m2v = a1; }
        rv[t] = m1v; ri[t] = c1v; rm2[t] = m2v;
        __syncthreads();
        for (int s = 128; s > 0; s >>= 1) {
            if (t < s) {
                float o1 = rv[t + s]; int oc = ri[t + s]; float o2 = rm2[t + s];
                float c1m = rv[t];
                if (o1 < c1m) { rv[t] = o1; ri[t] = oc; rm2[t] = fminf(o2, c1m); }
                else          { rm2[t] = fminf(rm2[t], o1); }
            }
            __syncthreads();
        }
        if (t == 0) { rmin1[i] = rv[0]; rc1[i] = ri[0]; rmin2[i] = rm2[0]; }
    }
}

// Kernel D (cheap): per-task term from cached per-row class minima.
__global__ void __launch_bounds__(256) terms_kernel(
        const int* __restrict__ labels, const int* __restrict__ negs1,
        const float* __restrict__ d_an, const float* __restrict__ d_ap,
        const int* __restrict__ avalid, const float* __restrict__ rmin1,
        const int* __restrict__ rc1, const float* __restrict__ rmin2,
        float* __restrict__ terms, float* __restrict__ validf) {
    int task = blockIdx.x * 256 + threadIdx.x;
    if (task >= N * K_NEG) return;
    int i = task / K_NEG;
    int n1 = negs1[task];
    int lab = labels[i];
    const float INF = __int_as_float(0x7f800000);
    float dn2 = (rc1[n1] == lab) ? rmin2[n1] : rmin1[n1];
    float dan = d_an[task];
    float dap = d_ap[i];
    float t1 = fmaxf(dap - dan + M1, 0.0f);
    float t2 = fmaxf(dap - dn2 + M2, 0.0f);
    bool valid = (avalid[i] != 0) && (dan < INF) && (dn2 < INF);
    terms[task]  = valid ? (t1 + t2) : 0.0f;
    validf[task] = valid ? 1.0f : 0.0f;
}

// Kernel E: deterministic final reduction.
__global__ void __launch_bounds__(256) finalize_kernel(
        const float* __restrict__ terms, const float* __restrict__ validf,
        const float* __restrict__ centerp, float* __restrict__ out) {
    int t = threadIdx.x;
    float ts = 0.f, vs = 0.f, cs = 0.f;
    for (int j = t; j < N * K_NEG; j += 256) { ts += terms[j]; vs += validf[j]; }
    for (int j = t; j < N; j += 256) cs += centerp[j];
    __shared__ float a[256], b[256], c[256];
    a[t] = ts; b[t] = vs; c[t] = cs;
    __syncthreads();
    for (int s = 128; s > 0; s >>= 1) {
        if (t < s) { a[t] += a[t + s]; b[t] += b[t + s]; c[t] += c[t + s]; }
        __syncthreads();
    }
    if (t == 0) {
        float quad = (b[0] > 0.0f) ? (a[0] / b[0]) : 0.0f;
        out[0] = quad + CW * (c[0] / (float)N);
    }
}

extern "C" void kernel_launch(void* const* d_in, const int* in_sizes, int n_in,
                              void* d_out, int out_size, void* d_ws, size_t ws_size,
                              hipStream_t stream) {
    const float* emb     = (const float*)d_in[0];
    const int*   labels  = (const int*)d_in[1];
    const float* centers = (const float*)d_in[2];
    float* out = (float*)d_out;

    char* ws = (char*)d_ws;
    unsigned short* xbf = (unsigned short*)ws;                 // 8 MB
    float* dist = (float*)(ws + (size_t)8 * 1024 * 1024);      // 16 MB
    char* p = ws + (size_t)24 * 1024 * 1024;
    float* sq      = (float*)p; p += N * 4;
    float* centerp = (float*)p; p += N * 4;
    float* d_ap    = (float*)p; p += N * 4;
    int*   avalid  = (int*)p;   p += N * 4;
    float* rmin1   = (float*)p; p += N * 4;
    int*   rc1     = (int*)p;   p += N * 4;
    float* rmin2   = (float*)p; p += N * 4;
    int*   negs1   = (int*)p;   p += N * K_NEG * 4;
    float* d_an    = (float*)p; p += N * K_NEG * 4;
    float* terms   = (float*)p; p += N * K_NEG * 4;
    float* validf  = (float*)p; p += N * K_NEG * 4;

    prep_kernel<<<N, 256, 0, stream>>>(emb, labels, centers, xbf, sq, centerp);
    dim3 g(N / BN, N / BM);
    gemm_dist_kernel<<<g, 512, 0, stream>>>(xbf, sq, dist);
    topk_kernel<<<N, 256, 0, stream>>>(dist, labels, d_ap, avalid, negs1, d_an,
                                       rmin1, rc1, rmin2);
    terms_kernel<<<(N * K_NEG + 255) / 256, 256, 0, stream>>>(
        labels, negs1, d_an, d_ap, avalid, rmin1, rc1, rmin2, terms, validf);
    finalize_kernel<<<1, 256, 0, stream>>>(terms, validf, centerp, out);
}